// Round 1
// baseline (571.113 us; speedup 1.0000x reference)
//
#include <hip/hip_runtime.h>
#include <hip/hip_fp16.h>

// Problem constants
#define BB 2
#define HH 16
#define SS 2048
#define DD 1024
#define DHH 64
#define SCALE_F 0.125f

typedef _Float16 half8 __attribute__((ext_vector_type(8)));
typedef float floatx4 __attribute__((ext_vector_type(4)));

__device__ __forceinline__ floatx4 mfma16(half8 a, half8 b, floatx4 c) {
  return __builtin_amdgcn_mfma_f32_16x16x32_f16(a, b, c, 0, 0, 0);
}

// ---------------------------------------------------------------------------
// Stage 1: QKV projection.  out[64 rows x 64 cols] per (mtile, head, type).
// q,k stored fp32 [B,H,S,DH]; v stored f16 transposed [B,H,DH,S].
// Split-f16 (hi+lo, 3 products) for ~fp32 accuracy.
// ---------------------------------------------------------------------------
__global__ __launch_bounds__(256) void qkv_proj_kernel(
    const float* __restrict__ tokens, const float* __restrict__ wq,
    const float* __restrict__ wk, const float* __restrict__ wv,
    float* __restrict__ qo, float* __restrict__ ko, _Float16* __restrict__ vto)
{
  __shared__ _Float16 Ah[64][40], Al[64][40];   // tokens tile [row][k], Kt=32, pad->40 (80B stride, 16B mult)
  __shared__ _Float16 Bh[64][40], Bl[64][40];   // weight tile transposed [col][k]

  const int mt = blockIdx.x;          // 0..63  (64-row tile of 4096 token rows)
  const int h  = blockIdx.y;          // 0..15
  const int z  = blockIdx.z;          // 0: q, 1: k, 2: v
  const float* w = (z == 0) ? wq : (z == 1) ? wk : wv;

  const int tid  = (int)threadIdx.x;
  const int lane = tid & 63, wid = tid >> 6;
  const int l16  = lane & 15, q4 = lane >> 4;
  const int m0   = mt * 64;

  const floatx4 z4 = {0.0f, 0.0f, 0.0f, 0.0f};
  floatx4 acc[4];
  #pragma unroll
  for (int n = 0; n < 4; ++n) acc[n] = z4;

  for (int kt = 0; kt < 32; ++kt) {
    __syncthreads();
    {
      // stage tokens tile: 64 rows x 32 k, 8 fp32 per thread
      const int row = tid >> 2, k0 = (tid & 3) * 8;
      const floatx4* tp = (const floatx4*)(tokens + (m0 + row) * DD + kt * 32 + k0);
      floatx4 x0 = tp[0], x1 = tp[1];
      #pragma unroll
      for (int i = 0; i < 8; ++i) {
        float x = (i < 4) ? x0[i] : x1[i - 4];
        _Float16 hi = (_Float16)x;
        Ah[row][k0 + i] = hi;
        Al[row][k0 + i] = (_Float16)(x - (float)hi);
      }
      // stage weight tile transposed: w[h][k][col] -> Bh[col][k]
      const int kk = tid >> 3, c0 = (tid & 7) * 8;
      const floatx4* wp = (const floatx4*)(w + h * (DD * DHH) + (kt * 32 + kk) * DHH + c0);
      floatx4 y0 = wp[0], y1 = wp[1];
      #pragma unroll
      for (int i = 0; i < 8; ++i) {
        float x = (i < 4) ? y0[i] : y1[i - 4];
        _Float16 hi = (_Float16)x;
        Bh[c0 + i][kk] = hi;
        Bl[c0 + i][kk] = (_Float16)(x - (float)hi);
      }
    }
    __syncthreads();

    const half8 a_h = *(const half8*)&Ah[16 * wid + l16][q4 * 8];
    const half8 a_l = *(const half8*)&Al[16 * wid + l16][q4 * 8];
    #pragma unroll
    for (int n = 0; n < 4; ++n) {
      const half8 b_h = *(const half8*)&Bh[n * 16 + l16][q4 * 8];
      const half8 b_l = *(const half8*)&Bl[n * 16 + l16][q4 * 8];
      acc[n] = mfma16(a_h, b_h, acc[n]);
      acc[n] = mfma16(a_h, b_l, acc[n]);
      acc[n] = mfma16(a_l, b_h, acc[n]);
    }
  }

  // epilogue: C layout row=(lane>>4)*4+r, col=lane&15
  #pragma unroll
  for (int n = 0; n < 4; ++n) {
    #pragma unroll
    for (int r = 0; r < 4; ++r) {
      const int grow = m0 + 16 * wid + q4 * 4 + r;   // 0..4095 = b*2048+s
      const int b = grow >> 11, s = grow & 2047;
      const int e = n * 16 + l16;
      const float v = acc[n][r];
      if (z == 0)      qo[((b * HH + h) * SS + s) * DHH + e] = v;
      else if (z == 1) ko[((b * HH + h) * SS + s) * DHH + e] = v;
      else             vto[((b * HH + h) * DHH + e) * SS + s] = (_Float16)v;
    }
  }
}

// ---------------------------------------------------------------------------
// Stage 2: flash attention.  Block = (b,h,64-row q tile), 4 waves, wave w owns
// q rows [16w,16w+16).  Split-f16 QK^T (3 products) -> online softmax -> f16 PV.
// ---------------------------------------------------------------------------
__global__ __launch_bounds__(256) void attn_kernel(
    const float* __restrict__ qw, const float* __restrict__ kw,
    const _Float16* __restrict__ vtw, float* __restrict__ aggw)
{
  __shared__ _Float16 Kh[64][72], Kl[64][72];   // key tile [key][e], stride 72 (144B, 16B mult)
  __shared__ _Float16 Vs[64][72];               // v tile [e][key]
  __shared__ _Float16 Ps[64][72];               // P tile [qrow][key], wave-private rows

  const int qt = blockIdx.x;   // 0..31
  const int h  = blockIdx.y;   // 0..15
  const int b  = blockIdx.z;   // 0..1
  const int tid  = (int)threadIdx.x;
  const int lane = tid & 63, wid = tid >> 6;
  const int l16  = lane & 15, q4 = lane >> 4;
  const int bh   = b * HH + h;

  // Q fragments in registers (A layout: m=lane&15, k=quad*8+j, 2 chunks of K=32)
  half8 qh[2], ql[2];
  {
    const float* qp = qw + ((bh * SS) + qt * 64 + 16 * wid + l16) * DHH;
    #pragma unroll
    for (int kc = 0; kc < 2; ++kc) {
      const floatx4* p = (const floatx4*)(qp + q4 * 8 + kc * 32);
      floatx4 x0 = p[0], x1 = p[1];
      #pragma unroll
      for (int j = 0; j < 8; ++j) {
        float x = ((j < 4) ? x0[j] : x1[j - 4]) * SCALE_F;
        _Float16 hi = (_Float16)x;
        qh[kc][j] = hi;
        ql[kc][j] = (_Float16)(x - (float)hi);
      }
    }
  }

  const floatx4 z4 = {0.0f, 0.0f, 0.0f, 0.0f};
  float m_r[4], l_r[4];
  floatx4 o[4];
  #pragma unroll
  for (int r = 0; r < 4; ++r) { m_r[r] = -1e30f; l_r[r] = 0.0f; }
  #pragma unroll
  for (int n = 0; n < 4; ++n) o[n] = z4;

  const float LOG2E = 1.4426950408889634f;

  for (int kt = 0; kt < 32; ++kt) {
    __syncthreads();   // protect LDS tiles from previous iteration's readers
    {
      const int row = tid >> 2, c0 = (tid & 3) * 16;
      // K tile: fp32 -> hi/lo f16
      const floatx4* kp = (const floatx4*)(kw + ((bh * SS) + kt * 64 + row) * DHH + c0);
      #pragma unroll
      for (int u = 0; u < 4; ++u) {
        floatx4 x = kp[u];
        #pragma unroll
        for (int i = 0; i < 4; ++i) {
          float f = x[i];
          _Float16 hi = (_Float16)f;
          Kh[row][c0 + u * 4 + i] = hi;
          Kl[row][c0 + u * 4 + i] = (_Float16)(f - (float)hi);
        }
      }
      // V tile (already f16, transposed [e][key])
      const half8* vp = (const half8*)(vtw + (bh * DHH + row) * SS + kt * 64 + c0);
      *(half8*)&Vs[row][c0]     = vp[0];
      *(half8*)&Vs[row][c0 + 8] = vp[1];
    }
    __syncthreads();

    // S = q @ k^T  (split: qh*kh + qh*kl + ql*kh)
    floatx4 sv[4];
    #pragma unroll
    for (int n = 0; n < 4; ++n) {
      sv[n] = z4;
      #pragma unroll
      for (int kc = 0; kc < 2; ++kc) {
        const half8 b_h = *(const half8*)&Kh[n * 16 + l16][q4 * 8 + kc * 32];
        const half8 b_l = *(const half8*)&Kl[n * 16 + l16][q4 * 8 + kc * 32];
        sv[n] = mfma16(qh[kc], b_h, sv[n]);
        sv[n] = mfma16(qh[kc], b_l, sv[n]);
        sv[n] = mfma16(ql[kc], b_h, sv[n]);
      }
    }

    // online softmax: row = 16*wid + q4*4 + r, cols spread over l16 and n
    #pragma unroll
    for (int r = 0; r < 4; ++r) {
      float mx = fmaxf(fmaxf(sv[0][r], sv[1][r]), fmaxf(sv[2][r], sv[3][r]));
      #pragma unroll
      for (int off = 1; off < 16; off <<= 1)
        mx = fmaxf(mx, __shfl_xor(mx, off));
      const float mnew = fmaxf(m_r[r], mx);
      const float alpha = exp2f((m_r[r] - mnew) * LOG2E);
      float psum = 0.0f;
      #pragma unroll
      for (int n = 0; n < 4; ++n) {
        float p = exp2f((sv[n][r] - mnew) * LOG2E);
        sv[n][r] = p;
        psum += p;
      }
      #pragma unroll
      for (int off = 1; off < 16; off <<= 1)
        psum += __shfl_xor(psum, off);
      l_r[r] = l_r[r] * alpha + psum;
      m_r[r] = mnew;
      #pragma unroll
      for (int n = 0; n < 4; ++n) o[n][r] *= alpha;
    }

    // P: C layout -> LDS -> A layout (wave-private rows, no barrier needed)
    #pragma unroll
    for (int n = 0; n < 4; ++n)
      #pragma unroll
      for (int r = 0; r < 4; ++r)
        Ps[16 * wid + q4 * 4 + r][n * 16 + l16] = (_Float16)sv[n][r];

    asm volatile("s_waitcnt lgkmcnt(0)" ::: "memory");

    const half8 pa0 = *(const half8*)&Ps[16 * wid + l16][q4 * 8];
    const half8 pa1 = *(const half8*)&Ps[16 * wid + l16][q4 * 8 + 32];
    #pragma unroll
    for (int n = 0; n < 4; ++n) {
      const half8 vb0 = *(const half8*)&Vs[n * 16 + l16][q4 * 8];
      const half8 vb1 = *(const half8*)&Vs[n * 16 + l16][q4 * 8 + 32];
      o[n] = mfma16(pa0, vb0, o[n]);
      o[n] = mfma16(pa1, vb1, o[n]);
    }
  }

  // normalize + store agg as [B, S, H*DH]
  #pragma unroll
  for (int r = 0; r < 4; ++r) {
    const float inv = 1.0f / l_r[r];
    const int s = qt * 64 + 16 * wid + q4 * 4 + r;
    #pragma unroll
    for (int n = 0; n < 4; ++n) {
      const int e = n * 16 + l16;
      aggw[(b * SS + s) * (HH * DHH) + h * DHH + e] = o[n][r] * inv;
    }
  }
}

// ---------------------------------------------------------------------------
// Stage 3: output projection.  out[4096,1024] = agg[4096,1024] @ wo_flat[1024,1024]
// (wo [H,DH,D] flat is exactly the [H*DH, D] matrix).  Split-f16, 3 products.
// ---------------------------------------------------------------------------
__global__ __launch_bounds__(256) void out_proj_kernel(
    const float* __restrict__ aggw, const float* __restrict__ wo,
    float* __restrict__ out)
{
  __shared__ _Float16 Ah[64][40], Al[64][40];
  __shared__ _Float16 Bh[64][40], Bl[64][40];   // wo tile transposed [col][k]

  const int nt = blockIdx.x;   // 0..15
  const int mt = blockIdx.y;   // 0..63
  const int tid  = (int)threadIdx.x;
  const int lane = tid & 63, wid = tid >> 6;
  const int l16  = lane & 15, q4 = lane >> 4;
  const int m0 = mt * 64, n0 = nt * 64;

  const floatx4 z4 = {0.0f, 0.0f, 0.0f, 0.0f};
  floatx4 acc[4];
  #pragma unroll
  for (int n = 0; n < 4; ++n) acc[n] = z4;

  for (int kt = 0; kt < 32; ++kt) {
    __syncthreads();
    {
      const int row = tid >> 2, k0 = (tid & 3) * 8;
      const floatx4* ap = (const floatx4*)(aggw + (m0 + row) * 1024 + kt * 32 + k0);
      floatx4 x0 = ap[0], x1 = ap[1];
      #pragma unroll
      for (int i = 0; i < 8; ++i) {
        float x = (i < 4) ? x0[i] : x1[i - 4];
        _Float16 hi = (_Float16)x;
        Ah[row][k0 + i] = hi;
        Al[row][k0 + i] = (_Float16)(x - (float)hi);
      }
      const int kk = tid >> 3, c0 = (tid & 7) * 8;
      const floatx4* wp = (const floatx4*)(wo + (kt * 32 + kk) * 1024 + n0 + c0);
      floatx4 y0 = wp[0], y1 = wp[1];
      #pragma unroll
      for (int i = 0; i < 8; ++i) {
        float x = (i < 4) ? y0[i] : y1[i - 4];
        _Float16 hi = (_Float16)x;
        Bh[c0 + i][kk] = hi;
        Bl[c0 + i][kk] = (_Float16)(x - (float)hi);
      }
    }
    __syncthreads();

    const half8 a_h = *(const half8*)&Ah[16 * wid + l16][q4 * 8];
    const half8 a_l = *(const half8*)&Al[16 * wid + l16][q4 * 8];
    #pragma unroll
    for (int n = 0; n < 4; ++n) {
      const half8 b_h = *(const half8*)&Bh[n * 16 + l16][q4 * 8];
      const half8 b_l = *(const half8*)&Bl[n * 16 + l16][q4 * 8];
      acc[n] = mfma16(a_h, b_h, acc[n]);
      acc[n] = mfma16(a_h, b_l, acc[n]);
      acc[n] = mfma16(a_l, b_h, acc[n]);
    }
  }

  #pragma unroll
  for (int n = 0; n < 4; ++n)
    #pragma unroll
    for (int r = 0; r < 4; ++r)
      out[(m0 + 16 * wid + q4 * 4 + r) * 1024 + n0 + n * 16 + l16] = acc[n][r];
}

// ---------------------------------------------------------------------------
extern "C" void kernel_launch(void* const* d_in, const int* in_sizes, int n_in,
                              void* d_out, int out_size, void* d_ws, size_t ws_size,
                              hipStream_t stream)
{
  const float* tokens = (const float*)d_in[0];
  const float* wq = (const float*)d_in[1];
  const float* wk = (const float*)d_in[2];
  const float* wv = (const float*)d_in[3];
  const float* wo = (const float*)d_in[4];
  float* out = (float*)d_out;

  char* ws = (char*)d_ws;
  // q: 16.78MB fp32, k: 16.78MB fp32, vt: 8.39MB f16, agg: 16.78MB fp32  (~58.7MB)
  float*    qw   = (float*)(ws);
  float*    kw   = (float*)(ws + 16777216);
  _Float16* vtw  = (_Float16*)(ws + 2 * 16777216);
  float*    aggw = (float*)(ws + 2 * 16777216 + 8388608);

  qkv_proj_kernel<<<dim3(64, 16, 3), 256, 0, stream>>>(tokens, wq, wk, wv, qw, kw, vtw);
  attn_kernel<<<dim3(32, 16, 2), 256, 0, stream>>>(qw, kw, vtw, aggw);
  out_proj_kernel<<<dim3(16, 64), 256, 0, stream>>>(aggw, wo, out);
}

// Round 2
// 363.218 us; speedup vs baseline: 1.5724x; 1.5724x over previous
//
#include <hip/hip_runtime.h>
#include <hip/hip_fp16.h>

// Problem constants
#define BB 2
#define HH 16
#define SS 2048
#define DD 1024
#define DHH 64
#define SCALE_F 0.125f

typedef _Float16 half8 __attribute__((ext_vector_type(8)));
typedef float floatx4 __attribute__((ext_vector_type(4)));

__device__ __forceinline__ floatx4 mfma16(half8 a, half8 b, floatx4 c) {
  return __builtin_amdgcn_mfma_f32_16x16x32_f16(a, b, c, 0, 0, 0);
}

// ---------------------------------------------------------------------------
// Kernel 0: weight conversion (once per call).
//  z<3 : w_z[h] fp32 [1024 k][64 e]  -> Wh/Wl f16 [n=z*1024+h*64+e][1024 k]
//  z==3: wo flat fp32 [1024 k][1024 d] -> Wot f16 [n=d][1024 k]   (single f16)
// 64x64 tile transpose through LDS.
// ---------------------------------------------------------------------------
__global__ __launch_bounds__(256) void convert_kernel(
    const float* __restrict__ wq, const float* __restrict__ wk,
    const float* __restrict__ wv, const float* __restrict__ wo,
    _Float16* __restrict__ Wh, _Float16* __restrict__ Wl,
    _Float16* __restrict__ Wot)
{
  __shared__ float St[64][68];
  const int kt = blockIdx.x;       // k-tile (64 rows)
  const int hy = blockIdx.y;       // h (z<3) or d-tile (z==3)
  const int z  = blockIdx.z;
  const int t  = (int)threadIdx.x;
  const int k0 = kt * 64;

  const float* src = (z == 0) ? (wq + hy * (DD * DHH))
                   : (z == 1) ? (wk + hy * (DD * DHH))
                   : (z == 2) ? (wv + hy * (DD * DHH))
                   : wo;

  const int rr = t >> 4, cc = (t & 15) * 4;
  if (z < 3) {
    #pragma unroll
    for (int i = 0; i < 4; ++i)
      *(floatx4*)&St[rr + 16 * i][cc] =
          *(const floatx4*)(src + (k0 + rr + 16 * i) * DHH + cc);
  } else {
    const int d0 = hy * 64;
    #pragma unroll
    for (int i = 0; i < 4; ++i)
      *(floatx4*)&St[rr + 16 * i][cc] =
          *(const floatx4*)(src + (k0 + rr + 16 * i) * 1024 + d0 + cc);
  }
  __syncthreads();

  const int e = t >> 2, kc = (t & 3) * 16;
  if (z < 3) {
    const int n = z * 1024 + hy * 64 + e;
    half8 hi0, hi1, lo0, lo1;
    #pragma unroll
    for (int u = 0; u < 16; ++u) {
      float x = St[kc + u][e];
      _Float16 hh = (_Float16)x;
      _Float16 ll = (_Float16)(x - (float)hh);
      if (u < 8) { hi0[u] = hh; lo0[u] = ll; }
      else       { hi1[u - 8] = hh; lo1[u - 8] = ll; }
    }
    *(half8*)(Wh + n * 1024 + k0 + kc)     = hi0;
    *(half8*)(Wh + n * 1024 + k0 + kc + 8) = hi1;
    *(half8*)(Wl + n * 1024 + k0 + kc)     = lo0;
    *(half8*)(Wl + n * 1024 + k0 + kc + 8) = lo1;
  } else {
    const int d0 = hy * 64;
    half8 hi0, hi1;
    #pragma unroll
    for (int u = 0; u < 16; ++u) {
      _Float16 hh = (_Float16)St[kc + u][e];
      if (u < 8) hi0[u] = hh; else hi1[u - 8] = hh;
    }
    *(half8*)(Wot + (d0 + e) * 1024 + k0 + kc)     = hi0;
    *(half8*)(Wot + (d0 + e) * 1024 + k0 + kc + 8) = hi1;
  }
}

// ---------------------------------------------------------------------------
// Kernel 1: fused QKV GEMM.  C[4096 m][3072 n], 128x128 tiles, split-f16
// (3 products).  A (tokens fp32) converted hi/lo in registers during staging;
// B (Wh/Wl) pure copy.  Epilogue: q -> qh/ql (scaled), k -> kh/kl, v -> vT.
// ---------------------------------------------------------------------------
__global__ __launch_bounds__(256) void qkv_gemm_kernel(
    const float* __restrict__ tokens,
    const _Float16* __restrict__ Wh, const _Float16* __restrict__ Wl,
    _Float16* __restrict__ qh, _Float16* __restrict__ ql,
    _Float16* __restrict__ kh, _Float16* __restrict__ kl,
    _Float16* __restrict__ vt)
{
  __shared__ _Float16 Ah[128][40], Al[128][40], Bh[128][40], Bl[128][40];
  const int n0 = blockIdx.x * 128;   // 0..23
  const int m0 = blockIdx.y * 128;   // 0..31
  const int t = (int)threadIdx.x;
  const int lane = t & 63, wid = t >> 6;
  const int l16 = lane & 15, q4 = lane >> 4;
  const int mw = (wid & 1) * 64, nw = (wid >> 1) * 64;

  const floatx4 z4 = {0.0f, 0.0f, 0.0f, 0.0f};
  floatx4 acc[4][4];
  #pragma unroll
  for (int mi = 0; mi < 4; ++mi)
    #pragma unroll
    for (int ni = 0; ni < 4; ++ni) acc[mi][ni] = z4;

  for (int kt = 0; kt < 32; ++kt) {
    __syncthreads();
    #pragma unroll
    for (int j = 0; j < 2; ++j) {
      const int idx = t + 256 * j;
      const int r = idx >> 2, kc = (idx & 3) * 8;
      // A: fp32 -> hi/lo
      const float* ap = tokens + (m0 + r) * DD + kt * 32 + kc;
      floatx4 x0 = *(const floatx4*)ap;
      floatx4 x1 = *(const floatx4*)(ap + 4);
      half8 hv, lv;
      #pragma unroll
      for (int i = 0; i < 8; ++i) {
        float x = (i < 4) ? x0[i] : x1[i - 4];
        _Float16 hh = (_Float16)x;
        hv[i] = hh;
        lv[i] = (_Float16)(x - (float)hh);
      }
      *(half8*)&Ah[r][kc] = hv;
      *(half8*)&Al[r][kc] = lv;
      // B: pure copy
      const int boff = (n0 + r) * 1024 + kt * 32 + kc;
      *(half8*)&Bh[r][kc] = *(const half8*)(Wh + boff);
      *(half8*)&Bl[r][kc] = *(const half8*)(Wl + boff);
    }
    __syncthreads();

    half8 a_h[4], a_l[4];
    #pragma unroll
    for (int mi = 0; mi < 4; ++mi) {
      a_h[mi] = *(const half8*)&Ah[mw + mi * 16 + l16][q4 * 8];
      a_l[mi] = *(const half8*)&Al[mw + mi * 16 + l16][q4 * 8];
    }
    #pragma unroll
    for (int ni = 0; ni < 4; ++ni) {
      const half8 b_h = *(const half8*)&Bh[nw + ni * 16 + l16][q4 * 8];
      const half8 b_l = *(const half8*)&Bl[nw + ni * 16 + l16][q4 * 8];
      #pragma unroll
      for (int mi = 0; mi < 4; ++mi) {
        acc[mi][ni] = mfma16(a_h[mi], b_h, acc[mi][ni]);
        acc[mi][ni] = mfma16(a_h[mi], b_l, acc[mi][ni]);
        acc[mi][ni] = mfma16(a_l[mi], b_h, acc[mi][ni]);
      }
    }
  }

  // epilogue: C row=(q4*4+r within 16-tile), col=l16
  #pragma unroll
  for (int ni = 0; ni < 4; ++ni) {
    const int ncol = n0 + nw + ni * 16;          // multiple of 16
    const int z = ncol >> 10;
    const int h = (ncol >> 6) & 15;
    const int e = (ncol & 63) + l16;
    #pragma unroll
    for (int mi = 0; mi < 4; ++mi) {
      #pragma unroll
      for (int r = 0; r < 4; ++r) {
        const int grow = m0 + mw + mi * 16 + q4 * 4 + r;   // 0..4095
        const int b = grow >> 11, s = grow & 2047;
        const float v = acc[mi][ni][r];
        const int qkidx = ((b * HH + h) * SS + s) * DHH + e;
        if (z == 0) {
          const float vs = v * SCALE_F;
          const _Float16 hh = (_Float16)vs;
          qh[qkidx] = hh;
          ql[qkidx] = (_Float16)(vs - (float)hh);
        } else if (z == 1) {
          const _Float16 hh = (_Float16)v;
          kh[qkidx] = hh;
          kl[qkidx] = (_Float16)(v - (float)hh);
        } else {
          vt[((b * HH + h) * DHH + e) * SS + s] = (_Float16)v;
        }
      }
    }
  }
}

// ---------------------------------------------------------------------------
// Kernel 2: flash attention.  Block = (b, h, 128-row q tile), 4 waves, wave w
// owns q rows [32w, 32w+32) (2 m-tiles).  All staging = pure f16 b128 copies.
// ---------------------------------------------------------------------------
__global__ __launch_bounds__(256) void attn_kernel(
    const _Float16* __restrict__ qh, const _Float16* __restrict__ ql,
    const _Float16* __restrict__ kh, const _Float16* __restrict__ kl,
    const _Float16* __restrict__ vt, _Float16* __restrict__ agg)
{
  __shared__ _Float16 Kh[64][72], Kl[64][72], Vs[64][72];
  __shared__ _Float16 Ps[128][72];

  const int qt = blockIdx.x;   // 0..15
  const int h  = blockIdx.y;   // 0..15
  const int b  = blockIdx.z;   // 0..1
  const int bh = b * HH + h;
  const int t = (int)threadIdx.x;
  const int lane = t & 63, wid = t >> 6;
  const int l16 = lane & 15, q4 = lane >> 4;

  // Q fragments (A layout), hi/lo, 2 m-tiles x 2 k-chunks
  half8 qfh[2][2], qfl[2][2];
  #pragma unroll
  for (int mi = 0; mi < 2; ++mi) {
    const int s = qt * 128 + wid * 32 + mi * 16 + l16;
    const int base = (bh * SS + s) * DHH + q4 * 8;
    #pragma unroll
    for (int kc = 0; kc < 2; ++kc) {
      qfh[mi][kc] = *(const half8*)(qh + base + kc * 32);
      qfl[mi][kc] = *(const half8*)(ql + base + kc * 32);
    }
  }

  const floatx4 z4 = {0.0f, 0.0f, 0.0f, 0.0f};
  floatx4 o[2][4];
  float m_r[2][4], l_r[2][4];
  #pragma unroll
  for (int mi = 0; mi < 2; ++mi) {
    #pragma unroll
    for (int r = 0; r < 4; ++r) { m_r[mi][r] = -1e30f; l_r[mi][r] = 0.0f; }
    #pragma unroll
    for (int ni = 0; ni < 4; ++ni) o[mi][ni] = z4;
  }
  const float LOG2E = 1.4426950408889634f;

  for (int kt = 0; kt < 32; ++kt) {
    __syncthreads();
    #pragma unroll
    for (int j = 0; j < 2; ++j) {
      const int idx = t + 256 * j;
      const int r = idx >> 3, c = (idx & 7) * 8;
      const int gk = (bh * SS + kt * 64 + r) * DHH + c;
      *(half8*)&Kh[r][c] = *(const half8*)(kh + gk);
      *(half8*)&Kl[r][c] = *(const half8*)(kl + gk);
      *(half8*)&Vs[r][c] = *(const half8*)(vt + (bh * DHH + r) * SS + kt * 64 + c);
    }
    __syncthreads();

    // S = q k^T (split, 3 products per k-chunk)
    floatx4 sv[2][4];
    #pragma unroll
    for (int ni = 0; ni < 4; ++ni) {
      const half8 b_h0 = *(const half8*)&Kh[ni * 16 + l16][q4 * 8];
      const half8 b_h1 = *(const half8*)&Kh[ni * 16 + l16][q4 * 8 + 32];
      const half8 b_l0 = *(const half8*)&Kl[ni * 16 + l16][q4 * 8];
      const half8 b_l1 = *(const half8*)&Kl[ni * 16 + l16][q4 * 8 + 32];
      #pragma unroll
      for (int mi = 0; mi < 2; ++mi) {
        floatx4 s4 = z4;
        s4 = mfma16(qfh[mi][0], b_h0, s4);
        s4 = mfma16(qfh[mi][1], b_h1, s4);
        s4 = mfma16(qfh[mi][0], b_l0, s4);
        s4 = mfma16(qfh[mi][1], b_l1, s4);
        s4 = mfma16(qfl[mi][0], b_h0, s4);
        s4 = mfma16(qfl[mi][1], b_h1, s4);
        sv[mi][ni] = s4;
      }
    }

    // online softmax (rows spread over q4,r; cols over l16,ni)
    #pragma unroll
    for (int mi = 0; mi < 2; ++mi) {
      #pragma unroll
      for (int r = 0; r < 4; ++r) {
        float mx = fmaxf(fmaxf(sv[mi][0][r], sv[mi][1][r]),
                         fmaxf(sv[mi][2][r], sv[mi][3][r]));
        #pragma unroll
        for (int off = 1; off < 16; off <<= 1)
          mx = fmaxf(mx, __shfl_xor(mx, off));
        const float mnew = fmaxf(m_r[mi][r], mx);
        const float alpha = exp2f((m_r[mi][r] - mnew) * LOG2E);
        float psum = 0.0f;
        #pragma unroll
        for (int ni = 0; ni < 4; ++ni) {
          float p = exp2f((sv[mi][ni][r] - mnew) * LOG2E);
          sv[mi][ni][r] = p;
          psum += p;
        }
        #pragma unroll
        for (int off = 1; off < 16; off <<= 1)
          psum += __shfl_xor(psum, off);
        l_r[mi][r] = l_r[mi][r] * alpha + psum;
        m_r[mi][r] = mnew;
        #pragma unroll
        for (int ni = 0; ni < 4; ++ni) o[mi][ni][r] *= alpha;
      }
    }

    // P: C layout -> LDS -> A layout (wave-private rows)
    #pragma unroll
    for (int mi = 0; mi < 2; ++mi)
      #pragma unroll
      for (int ni = 0; ni < 4; ++ni)
        #pragma unroll
        for (int r = 0; r < 4; ++r)
          Ps[wid * 32 + mi * 16 + q4 * 4 + r][ni * 16 + l16] =
              (_Float16)sv[mi][ni][r];

    asm volatile("s_waitcnt lgkmcnt(0)" ::: "memory");

    #pragma unroll
    for (int mi = 0; mi < 2; ++mi) {
      const half8 pa0 = *(const half8*)&Ps[wid * 32 + mi * 16 + l16][q4 * 8];
      const half8 pa1 = *(const half8*)&Ps[wid * 32 + mi * 16 + l16][q4 * 8 + 32];
      #pragma unroll
      for (int ni = 0; ni < 4; ++ni) {
        const half8 vb0 = *(const half8*)&Vs[ni * 16 + l16][q4 * 8];
        const half8 vb1 = *(const half8*)&Vs[ni * 16 + l16][q4 * 8 + 32];
        o[mi][ni] = mfma16(pa0, vb0, o[mi][ni]);
        o[mi][ni] = mfma16(pa1, vb1, o[mi][ni]);
      }
    }
  }

  // normalize + store agg f16 [b][s][h*64+e]
  #pragma unroll
  for (int mi = 0; mi < 2; ++mi) {
    #pragma unroll
    for (int r = 0; r < 4; ++r) {
      const float inv = 1.0f / l_r[mi][r];
      const int s = qt * 128 + wid * 32 + mi * 16 + q4 * 4 + r;
      #pragma unroll
      for (int ni = 0; ni < 4; ++ni) {
        const int e = ni * 16 + l16;
        agg[(b * SS + s) * (HH * DHH) + h * DHH + e] =
            (_Float16)(o[mi][ni][r] * inv);
      }
    }
  }
}

// ---------------------------------------------------------------------------
// Kernel 3: output projection.  out[4096,1024] = agg @ Wot^T, single f16.
// ---------------------------------------------------------------------------
__global__ __launch_bounds__(256) void out_gemm_kernel(
    const _Float16* __restrict__ agg, const _Float16* __restrict__ Wot,
    float* __restrict__ out)
{
  __shared__ _Float16 As[128][40], Bs[128][40];
  const int n0 = blockIdx.x * 128;   // 0..7
  const int m0 = blockIdx.y * 128;   // 0..31
  const int t = (int)threadIdx.x;
  const int lane = t & 63, wid = t >> 6;
  const int l16 = lane & 15, q4 = lane >> 4;
  const int mw = (wid & 1) * 64, nw = (wid >> 1) * 64;

  const floatx4 z4 = {0.0f, 0.0f, 0.0f, 0.0f};
  floatx4 acc[4][4];
  #pragma unroll
  for (int mi = 0; mi < 4; ++mi)
    #pragma unroll
    for (int ni = 0; ni < 4; ++ni) acc[mi][ni] = z4;

  for (int kt = 0; kt < 32; ++kt) {
    __syncthreads();
    #pragma unroll
    for (int j = 0; j < 2; ++j) {
      const int idx = t + 256 * j;
      const int r = idx >> 2, kc = (idx & 3) * 8;
      *(half8*)&As[r][kc] = *(const half8*)(agg + (m0 + r) * 1024 + kt * 32 + kc);
      *(half8*)&Bs[r][kc] = *(const half8*)(Wot + (n0 + r) * 1024 + kt * 32 + kc);
    }
    __syncthreads();

    half8 a_f[4];
    #pragma unroll
    for (int mi = 0; mi < 4; ++mi)
      a_f[mi] = *(const half8*)&As[mw + mi * 16 + l16][q4 * 8];
    #pragma unroll
    for (int ni = 0; ni < 4; ++ni) {
      const half8 b_f = *(const half8*)&Bs[nw + ni * 16 + l16][q4 * 8];
      #pragma unroll
      for (int mi = 0; mi < 4; ++mi)
        acc[mi][ni] = mfma16(a_f[mi], b_f, acc[mi][ni]);
    }
  }

  #pragma unroll
  for (int ni = 0; ni < 4; ++ni)
    #pragma unroll
    for (int mi = 0; mi < 4; ++mi)
      #pragma unroll
      for (int r = 0; r < 4; ++r)
        out[(m0 + mw + mi * 16 + q4 * 4 + r) * 1024 + n0 + nw + ni * 16 + l16] =
            acc[mi][ni][r];
}

// ---------------------------------------------------------------------------
extern "C" void kernel_launch(void* const* d_in, const int* in_sizes, int n_in,
                              void* d_out, int out_size, void* d_ws, size_t ws_size,
                              hipStream_t stream)
{
  const float* tokens = (const float*)d_in[0];
  const float* wq = (const float*)d_in[1];
  const float* wk = (const float*)d_in[2];
  const float* wv = (const float*)d_in[3];
  const float* wo = (const float*)d_in[4];
  float* out = (float*)d_out;

  char* ws = (char*)d_ws;
  // layout (bytes):
  //   qh 0          (8388608)   ql 8388608   kh 16777216   kl 25165824
  //   vt 33554432   (8388608)
  //   Wh 41943040   (6291456)   Wl 48234496  (6291456)
  //   Wot 54525952  (2097152)           total 56623104
  //   agg aliases Wh/Wl (41943040, 8388608) -- Wh/Wl dead after qkv_gemm
  _Float16* qh  = (_Float16*)(ws);
  _Float16* ql  = (_Float16*)(ws + 8388608);
  _Float16* kh  = (_Float16*)(ws + 16777216);
  _Float16* kl  = (_Float16*)(ws + 25165824);
  _Float16* vt  = (_Float16*)(ws + 33554432);
  _Float16* Wh  = (_Float16*)(ws + 41943040);
  _Float16* Wl  = (_Float16*)(ws + 48234496);
  _Float16* Wot = (_Float16*)(ws + 54525952);
  _Float16* agg = (_Float16*)(ws + 41943040);

  convert_kernel<<<dim3(16, 16, 4), 256, 0, stream>>>(wq, wk, wv, wo, Wh, Wl, Wot);
  qkv_gemm_kernel<<<dim3(24, 32), 256, 0, stream>>>(tokens, Wh, Wl, qh, ql, kh, kl, vt);
  attn_kernel<<<dim3(16, 16, 2), 256, 0, stream>>>(qh, ql, kh, kl, vt, agg);
  out_gemm_kernel<<<dim3(8, 32), 256, 0, stream>>>(agg, Wot, out);
}

// Round 3
// 328.671 us; speedup vs baseline: 1.7376x; 1.1051x over previous
//
#include <hip/hip_runtime.h>
#include <hip/hip_fp16.h>

// Problem constants
#define BB 2
#define HH 16
#define SS 2048
#define DD 1024
#define DHH 64
// SCALE * log2(e): logits computed directly in log2 domain
#define QSCALE 0.18033688011112042f

typedef _Float16 half8 __attribute__((ext_vector_type(8)));
typedef _Float16 half4 __attribute__((ext_vector_type(4)));
typedef float floatx4 __attribute__((ext_vector_type(4)));

__device__ __forceinline__ floatx4 mfma16(half8 a, half8 b, floatx4 c) {
  return __builtin_amdgcn_mfma_f32_16x16x32_f16(a, b, c, 0, 0, 0);
}

// ---------------------------------------------------------------------------
// Kernel 0: weight conversion (once per call).
//  z<3 : w_z[h] fp32 [1024 k][64 e]  -> Wh/Wl f16 [n=z*1024+h*64+e][1024 k]
//  z==3: wo flat fp32 [1024 k][1024 d] -> Wot f16 [n=d][1024 k]   (single f16)
// ---------------------------------------------------------------------------
__global__ __launch_bounds__(256) void convert_kernel(
    const float* __restrict__ wq, const float* __restrict__ wk,
    const float* __restrict__ wv, const float* __restrict__ wo,
    _Float16* __restrict__ Wh, _Float16* __restrict__ Wl,
    _Float16* __restrict__ Wot)
{
  __shared__ float St[64][68];
  const int kt = blockIdx.x;       // k-tile (64 rows)
  const int hy = blockIdx.y;       // h (z<3) or d-tile (z==3)
  const int z  = blockIdx.z;
  const int t  = (int)threadIdx.x;
  const int k0 = kt * 64;

  const float* src = (z == 0) ? (wq + hy * (DD * DHH))
                   : (z == 1) ? (wk + hy * (DD * DHH))
                   : (z == 2) ? (wv + hy * (DD * DHH))
                   : wo;

  const int rr = t >> 4, cc = (t & 15) * 4;
  if (z < 3) {
    #pragma unroll
    for (int i = 0; i < 4; ++i)
      *(floatx4*)&St[rr + 16 * i][cc] =
          *(const floatx4*)(src + (k0 + rr + 16 * i) * DHH + cc);
  } else {
    const int d0 = hy * 64;
    #pragma unroll
    for (int i = 0; i < 4; ++i)
      *(floatx4*)&St[rr + 16 * i][cc] =
          *(const floatx4*)(src + (k0 + rr + 16 * i) * 1024 + d0 + cc);
  }
  __syncthreads();

  const int e = t >> 2, kc = (t & 3) * 16;
  if (z < 3) {
    const int n = z * 1024 + hy * 64 + e;
    half8 hi0, hi1, lo0, lo1;
    #pragma unroll
    for (int u = 0; u < 16; ++u) {
      float x = St[kc + u][e];
      _Float16 hh = (_Float16)x;
      _Float16 ll = (_Float16)(x - (float)hh);
      if (u < 8) { hi0[u] = hh; lo0[u] = ll; }
      else       { hi1[u - 8] = hh; lo1[u - 8] = ll; }
    }
    *(half8*)(Wh + n * 1024 + k0 + kc)     = hi0;
    *(half8*)(Wh + n * 1024 + k0 + kc + 8) = hi1;
    *(half8*)(Wl + n * 1024 + k0 + kc)     = lo0;
    *(half8*)(Wl + n * 1024 + k0 + kc + 8) = lo1;
  } else {
    const int d0 = hy * 64;
    half8 hi0, hi1;
    #pragma unroll
    for (int u = 0; u < 16; ++u) {
      _Float16 hh = (_Float16)St[kc + u][e];
      if (u < 8) hi0[u] = hh; else hi1[u - 8] = hh;
    }
    *(half8*)(Wot + (d0 + e) * 1024 + k0 + kc)     = hi0;
    *(half8*)(Wot + (d0 + e) * 1024 + k0 + kc + 8) = hi1;
  }
}

// ---------------------------------------------------------------------------
// Kernel 1: fused QKV GEMM.  C[4096 m][3072 n], 128x128 tiles, split-f16
// (3 products).  Epilogue: q -> qh/ql (scaled by SCALE*log2e), k -> kh/kl,
// v -> vT f16.
// ---------------------------------------------------------------------------
__global__ __launch_bounds__(256) void qkv_gemm_kernel(
    const float* __restrict__ tokens,
    const _Float16* __restrict__ Wh, const _Float16* __restrict__ Wl,
    _Float16* __restrict__ qh, _Float16* __restrict__ ql,
    _Float16* __restrict__ kh, _Float16* __restrict__ kl,
    _Float16* __restrict__ vt)
{
  __shared__ _Float16 Ah[128][40], Al[128][40], Bh[128][40], Bl[128][40];
  const int n0 = blockIdx.x * 128;   // 0..23
  const int m0 = blockIdx.y * 128;   // 0..31
  const int t = (int)threadIdx.x;
  const int lane = t & 63, wid = t >> 6;
  const int l16 = lane & 15, q4 = lane >> 4;
  const int mw = (wid & 1) * 64, nw = (wid >> 1) * 64;

  const floatx4 z4 = {0.0f, 0.0f, 0.0f, 0.0f};
  floatx4 acc[4][4];
  #pragma unroll
  for (int mi = 0; mi < 4; ++mi)
    #pragma unroll
    for (int ni = 0; ni < 4; ++ni) acc[mi][ni] = z4;

  for (int kt = 0; kt < 32; ++kt) {
    __syncthreads();
    #pragma unroll
    for (int j = 0; j < 2; ++j) {
      const int idx = t + 256 * j;
      const int r = idx >> 2, kc = (idx & 3) * 8;
      const float* ap = tokens + (m0 + r) * DD + kt * 32 + kc;
      floatx4 x0 = *(const floatx4*)ap;
      floatx4 x1 = *(const floatx4*)(ap + 4);
      half8 hv, lv;
      #pragma unroll
      for (int i = 0; i < 8; ++i) {
        float x = (i < 4) ? x0[i] : x1[i - 4];
        _Float16 hh = (_Float16)x;
        hv[i] = hh;
        lv[i] = (_Float16)(x - (float)hh);
      }
      *(half8*)&Ah[r][kc] = hv;
      *(half8*)&Al[r][kc] = lv;
      const int boff = (n0 + r) * 1024 + kt * 32 + kc;
      *(half8*)&Bh[r][kc] = *(const half8*)(Wh + boff);
      *(half8*)&Bl[r][kc] = *(const half8*)(Wl + boff);
    }
    __syncthreads();

    half8 a_h[4], a_l[4];
    #pragma unroll
    for (int mi = 0; mi < 4; ++mi) {
      a_h[mi] = *(const half8*)&Ah[mw + mi * 16 + l16][q4 * 8];
      a_l[mi] = *(const half8*)&Al[mw + mi * 16 + l16][q4 * 8];
    }
    #pragma unroll
    for (int ni = 0; ni < 4; ++ni) {
      const half8 b_h = *(const half8*)&Bh[nw + ni * 16 + l16][q4 * 8];
      const half8 b_l = *(const half8*)&Bl[nw + ni * 16 + l16][q4 * 8];
      #pragma unroll
      for (int mi = 0; mi < 4; ++mi) {
        acc[mi][ni] = mfma16(a_h[mi], b_h, acc[mi][ni]);
        acc[mi][ni] = mfma16(a_h[mi], b_l, acc[mi][ni]);
        acc[mi][ni] = mfma16(a_l[mi], b_h, acc[mi][ni]);
      }
    }
  }

  #pragma unroll
  for (int ni = 0; ni < 4; ++ni) {
    const int ncol = n0 + nw + ni * 16;
    const int z = ncol >> 10;
    const int h = (ncol >> 6) & 15;
    const int e = (ncol & 63) + l16;
    #pragma unroll
    for (int mi = 0; mi < 4; ++mi) {
      #pragma unroll
      for (int r = 0; r < 4; ++r) {
        const int grow = m0 + mw + mi * 16 + q4 * 4 + r;
        const int b = grow >> 11, s = grow & 2047;
        const float v = acc[mi][ni][r];
        const int qkidx = ((b * HH + h) * SS + s) * DHH + e;
        if (z == 0) {
          const float vs = v * QSCALE;
          const _Float16 hh = (_Float16)vs;
          qh[qkidx] = hh;
          ql[qkidx] = (_Float16)(vs - (float)hh);
        } else if (z == 1) {
          const _Float16 hh = (_Float16)v;
          kh[qkidx] = hh;
          kl[qkidx] = (_Float16)(v - (float)hh);
        } else {
          vt[((b * HH + h) * DHH + e) * SS + s] = (_Float16)v;
        }
      }
    }
  }
}

// ---------------------------------------------------------------------------
// Kernel 2: flash attention, TRANSPOSED orientation.
// Block = (b, h, 64-query tile), 4 waves; wave w owns queries [16w,16w+16),
// with query index on the lane axis (n = l16) so the softmax reduction over
// keys is in-register (16 values) + 2 butterfly shuffles.
//   S^T = mfma(A=K-frag, B=Q-frag):  S^T[key=q4*4+r (+16*sub)][query=l16]
//   agg^T = mfma(A=V^T-frag, B=P-frag): agg^T[e=q4*4+r (+16*sub)][query=l16]
// Logits arrive pre-scaled by SCALE*log2e -> exp2 directly.
// ---------------------------------------------------------------------------
__global__ __launch_bounds__(256, 4) void attn_kernel(
    const _Float16* __restrict__ qh, const _Float16* __restrict__ ql,
    const _Float16* __restrict__ kh, const _Float16* __restrict__ kl,
    const _Float16* __restrict__ vt, _Float16* __restrict__ agg)
{
  __shared__ _Float16 Kh[64][72], Kl[64][72], Vs[64][72];
  __shared__ _Float16 Ps[64][72];   // [query][key], wave-private 16-row bands

  const int qt = blockIdx.x;   // 0..31
  const int h  = blockIdx.y;   // 0..15
  const int b  = blockIdx.z;   // 0..1
  const int bh = b * HH + h;
  const int t = (int)threadIdx.x;
  const int lane = t & 63, wid = t >> 6;
  const int l16 = lane & 15, q4 = lane >> 4;

  // Q fragments: Q[query][e]; query = qt*64 + wid*16 + l16 (lane axis)
  half8 qfh[2], qfl[2];
  {
    const int s = qt * 64 + wid * 16 + l16;
    const int base = (bh * SS + s) * DHH + q4 * 8;
    qfh[0] = *(const half8*)(qh + base);
    qfh[1] = *(const half8*)(qh + base + 32);
    qfl[0] = *(const half8*)(ql + base);
    qfl[1] = *(const half8*)(ql + base + 32);
  }

  const floatx4 z4 = {0.0f, 0.0f, 0.0f, 0.0f};
  floatx4 o[4];                 // agg^T accumulator: o[sub][r] = [e][this query]
  #pragma unroll
  for (int i = 0; i < 4; ++i) o[i] = z4;
  float m_r = -1e30f, l_r = 0.0f;

  for (int kt = 0; kt < 32; ++kt) {
    __syncthreads();
    #pragma unroll
    for (int j = 0; j < 2; ++j) {
      const int idx = t + 256 * j;
      const int r = idx >> 3, c = (idx & 7) * 8;
      const int gk = (bh * SS + kt * 64 + r) * DHH + c;
      *(half8*)&Kh[r][c] = *(const half8*)(kh + gk);
      *(half8*)&Kl[r][c] = *(const half8*)(kl + gk);
      *(half8*)&Vs[r][c] = *(const half8*)(vt + (bh * DHH + r) * SS + kt * 64 + c);
    }
    __syncthreads();

    // S^T = K . Q^T  (split: Kh*Qh + Kl*Qh + Kh*Ql), 64 keys x 16 queries
    floatx4 sv[4];
    #pragma unroll
    for (int sub = 0; sub < 4; ++sub) {
      const half8 ah0 = *(const half8*)&Kh[sub * 16 + l16][q4 * 8];
      const half8 ah1 = *(const half8*)&Kh[sub * 16 + l16][q4 * 8 + 32];
      const half8 al0 = *(const half8*)&Kl[sub * 16 + l16][q4 * 8];
      const half8 al1 = *(const half8*)&Kl[sub * 16 + l16][q4 * 8 + 32];
      floatx4 s4 = z4;
      s4 = mfma16(ah0, qfh[0], s4);
      s4 = mfma16(ah1, qfh[1], s4);
      s4 = mfma16(al0, qfh[0], s4);
      s4 = mfma16(al1, qfh[1], s4);
      s4 = mfma16(ah0, qfl[0], s4);
      s4 = mfma16(ah1, qfl[1], s4);
      sv[sub] = s4;
    }

    // online softmax (log2 domain); this lane owns one query's 16 logits
    float mx = fmaxf(fmaxf(sv[0][0], sv[0][1]), fmaxf(sv[0][2], sv[0][3]));
    #pragma unroll
    for (int sub = 1; sub < 4; ++sub)
      mx = fmaxf(mx, fmaxf(fmaxf(sv[sub][0], sv[sub][1]),
                           fmaxf(sv[sub][2], sv[sub][3])));
    mx = fmaxf(mx, __shfl_xor(mx, 16));
    mx = fmaxf(mx, __shfl_xor(mx, 32));
    const float mnew = fmaxf(m_r, mx);
    const float alpha = exp2f(m_r - mnew);
    float psum = 0.0f;
    #pragma unroll
    for (int sub = 0; sub < 4; ++sub) {
      #pragma unroll
      for (int r = 0; r < 4; ++r) {
        float p = exp2f(sv[sub][r] - mnew);
        sv[sub][r] = p;
        psum += p;
      }
    }
    psum += __shfl_xor(psum, 16);
    psum += __shfl_xor(psum, 32);
    l_r = l_r * alpha + psum;
    m_r = mnew;
    #pragma unroll
    for (int sub = 0; sub < 4; ++sub)
      #pragma unroll
      for (int r = 0; r < 4; ++r) o[sub][r] *= alpha;

    // P -> LDS [query][key]: 4 consecutive keys per store = ds_write_b64
    #pragma unroll
    for (int sub = 0; sub < 4; ++sub) {
      half4 pv;
      #pragma unroll
      for (int r = 0; r < 4; ++r) pv[r] = (_Float16)sv[sub][r];
      *(half4*)&Ps[wid * 16 + l16][sub * 16 + q4 * 4] = pv;
    }
    asm volatile("s_waitcnt lgkmcnt(0)" ::: "memory");

    // agg^T += V^T . P : A-frag from Vs[e][key], B-frag from Ps[query][key]
    const half8 pb0 = *(const half8*)&Ps[wid * 16 + l16][q4 * 8];
    const half8 pb1 = *(const half8*)&Ps[wid * 16 + l16][q4 * 8 + 32];
    #pragma unroll
    for (int sub = 0; sub < 4; ++sub) {
      const half8 va0 = *(const half8*)&Vs[sub * 16 + l16][q4 * 8];
      const half8 va1 = *(const half8*)&Vs[sub * 16 + l16][q4 * 8 + 32];
      o[sub] = mfma16(va0, pb0, o[sub]);
      o[sub] = mfma16(va1, pb1, o[sub]);
    }
  }

  // normalize + store agg f16 [b][s][h*64+e]; 4 consecutive e = b64 store
  const float inv = 1.0f / l_r;
  const int s = qt * 64 + wid * 16 + l16;
  #pragma unroll
  for (int sub = 0; sub < 4; ++sub) {
    half4 ov;
    #pragma unroll
    for (int r = 0; r < 4; ++r) ov[r] = (_Float16)(o[sub][r] * inv);
    *(half4*)(agg + (b * SS + s) * (HH * DHH) + h * DHH + sub * 16 + q4 * 4) = ov;
  }
}

// ---------------------------------------------------------------------------
// Kernel 3: output projection.  out[4096,1024] = agg @ Wot^T, single f16.
// ---------------------------------------------------------------------------
__global__ __launch_bounds__(256) void out_gemm_kernel(
    const _Float16* __restrict__ agg, const _Float16* __restrict__ Wot,
    float* __restrict__ out)
{
  __shared__ _Float16 As[128][40], Bs[128][40];
  const int n0 = blockIdx.x * 128;   // 0..7
  const int m0 = blockIdx.y * 128;   // 0..31
  const int t = (int)threadIdx.x;
  const int lane = t & 63, wid = t >> 6;
  const int l16 = lane & 15, q4 = lane >> 4;
  const int mw = (wid & 1) * 64, nw = (wid >> 1) * 64;

  const floatx4 z4 = {0.0f, 0.0f, 0.0f, 0.0f};
  floatx4 acc[4][4];
  #pragma unroll
  for (int mi = 0; mi < 4; ++mi)
    #pragma unroll
    for (int ni = 0; ni < 4; ++ni) acc[mi][ni] = z4;

  for (int kt = 0; kt < 32; ++kt) {
    __syncthreads();
    #pragma unroll
    for (int j = 0; j < 2; ++j) {
      const int idx = t + 256 * j;
      const int r = idx >> 2, kc = (idx & 3) * 8;
      *(half8*)&As[r][kc] = *(const half8*)(agg + (m0 + r) * 1024 + kt * 32 + kc);
      *(half8*)&Bs[r][kc] = *(const half8*)(Wot + (n0 + r) * 1024 + kt * 32 + kc);
    }
    __syncthreads();

    half8 a_f[4];
    #pragma unroll
    for (int mi = 0; mi < 4; ++mi)
      a_f[mi] = *(const half8*)&As[mw + mi * 16 + l16][q4 * 8];
    #pragma unroll
    for (int ni = 0; ni < 4; ++ni) {
      const half8 b_f = *(const half8*)&Bs[nw + ni * 16 + l16][q4 * 8];
      #pragma unroll
      for (int mi = 0; mi < 4; ++mi)
        acc[mi][ni] = mfma16(a_f[mi], b_f, acc[mi][ni]);
    }
  }

  #pragma unroll
  for (int ni = 0; ni < 4; ++ni)
    #pragma unroll
    for (int mi = 0; mi < 4; ++mi)
      #pragma unroll
      for (int r = 0; r < 4; ++r)
        out[(m0 + mw + mi * 16 + q4 * 4 + r) * 1024 + n0 + nw + ni * 16 + l16] =
            acc[mi][ni][r];
}

// ---------------------------------------------------------------------------
extern "C" void kernel_launch(void* const* d_in, const int* in_sizes, int n_in,
                              void* d_out, int out_size, void* d_ws, size_t ws_size,
                              hipStream_t stream)
{
  const float* tokens = (const float*)d_in[0];
  const float* wq = (const float*)d_in[1];
  const float* wk = (const float*)d_in[2];
  const float* wv = (const float*)d_in[3];
  const float* wo = (const float*)d_in[4];
  float* out = (float*)d_out;

  char* ws = (char*)d_ws;
  // layout (bytes):
  //   qh 0          (8388608)   ql 8388608   kh 16777216   kl 25165824
  //   vt 33554432   (8388608)
  //   Wh 41943040   (6291456)   Wl 48234496  (6291456)
  //   Wot 54525952  (2097152)           total 56623104
  //   agg aliases Wh/Wl (41943040, 8388608) -- Wh/Wl dead after qkv_gemm
  _Float16* qh  = (_Float16*)(ws);
  _Float16* ql  = (_Float16*)(ws + 8388608);
  _Float16* kh  = (_Float16*)(ws + 16777216);
  _Float16* kl  = (_Float16*)(ws + 25165824);
  _Float16* vt  = (_Float16*)(ws + 33554432);
  _Float16* Wh  = (_Float16*)(ws + 41943040);
  _Float16* Wl  = (_Float16*)(ws + 48234496);
  _Float16* Wot = (_Float16*)(ws + 54525952);
  _Float16* agg = (_Float16*)(ws + 41943040);

  convert_kernel<<<dim3(16, 16, 4), 256, 0, stream>>>(wq, wk, wv, wo, Wh, Wl, Wot);
  qkv_gemm_kernel<<<dim3(24, 32), 256, 0, stream>>>(tokens, Wh, Wl, qh, ql, kh, kl, vt);
  attn_kernel<<<dim3(32, 16, 2), 256, 0, stream>>>(qh, ql, kh, kl, vt, agg);
  out_gemm_kernel<<<dim3(8, 32), 256, 0, stream>>>(agg, Wot, out);
}